// Round 4
// baseline (128.274 us; speedup 1.0000x reference)
//
#include <hip/hip_runtime.h>

// Problem constants (from reference)
#define NSTARS 2048
#define BATCH  256
#define PF     28
#define NGE    512
#define GF     32
#define OPD2   65536   // 256*256
#define KTOT   (PF + GF)  // 60
#define TM     16      // batches per block in main kernel
#define KB     4       // k-slices per LDS tile
#define NT     (KTOT / KB)  // 15 tiles: 0..6 = S_poly (28 k), 7..14 = S_graph (32 k)

typedef float f32x4 __attribute__((ext_vector_type(4)));

// ---------------------------------------------------------------------------
// Kernel 1: index search + W = [interm_poly | interm_graph] (k-major layout)
// Wt[k*BATCH + b], k in [0,60)
// ---------------------------------------------------------------------------
__global__ __launch_bounds__(256) void prep_kernel(
    const float* __restrict__ positions,  const float* __restrict__ obs_pos,
    const float* __restrict__ poly_dic,   const float* __restrict__ graph_dic,
    const float* __restrict__ alpha_poly, const float* __restrict__ alpha_graph,
    float* __restrict__ Wt)
{
    const int b = blockIdx.x;   // batch row
    const int t = threadIdx.x;  // 256 threads

    const float p0 = positions[2 * b];
    const float p1 = positions[2 * b + 1];

    // Faithful to argmax(eq.reshape(B,-1))//2 : first star n (row-major over
    // (n, coord)) where EITHER coordinate matches; all-false -> 0.
    int cand = 0x7fffffff;
    #pragma unroll
    for (int i = 0; i < NSTARS / 256; ++i) {
        const int n = t + i * 256;
        const float o0 = obs_pos[2 * n];
        const float o1 = obs_pos[2 * n + 1];
        if (o0 == p0 || o1 == p1) cand = min(cand, n);
    }
    __shared__ int smin[256];
    smin[t] = cand;
    __syncthreads();
    for (int s = 128; s > 0; s >>= 1) {
        if (t < s) smin[t] = min(smin[t], smin[t + s]);
        __syncthreads();
    }
    int idx = smin[0];
    if (idx == 0x7fffffff) idx = 0;  // argmax of all-False returns 0

    // interm_poly[j] = sum_p poly_dic[idx,p] * alpha_poly[p,j]
    if (t < PF) {
        float acc = 0.f;
        #pragma unroll
        for (int p = 0; p < PF; ++p)
            acc += poly_dic[idx * PF + p] * alpha_poly[p * PF + t];
        Wt[t * BATCH + b] = acc;
    }

    // interm_graph[g] = sum_e graph_dic[idx,e] * alpha_graph[e,g]
    // 8 partials of 64 elements each, reduced in LDS.
    __shared__ float psum[8][GF];
    {
        const int g = t & 31;
        const int r = t >> 5;
        float acc = 0.f;
        const int e0 = r * (NGE / 8);
        for (int e = e0; e < e0 + NGE / 8; ++e)
            acc += graph_dic[idx * NGE + e] * alpha_graph[e * GF + g];
        psum[r][g] = acc;
    }
    __syncthreads();
    if (t < GF) {
        float acc = 0.f;
        #pragma unroll
        for (int r = 0; r < 8; ++r) acc += psum[r][t];
        Wt[(PF + t) * BATCH + b] = acc;
    }
}

// ---------------------------------------------------------------------------
// Kernel 2: out[b, ij] = sum_k Wt[k, b] * S[k, ij]
// TM=16 batches x 1024 ij per block, 1024 blocks, XCD-swizzled.
//
// Barrier-free counted-vmcnt pipeline (AITER/T4 style):
//   - each wave stages its OWN 64 lanes' float4s via global_load_lds and reads
//     back only that region -> no cross-wave sharing -> NO __syncthreads in
//     the k-loop (R3's per-tile vmcnt(0)+barrier drain was the stall).
//   - depth-2 prefetch: tiles T and T+1 always in flight; per tile wait
//     s_waitcnt vmcnt(4) (tile T landed, T+1 still flying) -- never 0.
//   - W is broadcast via LDS (read with same-address ds_read_b128, lgkm
//     domain) so the ONLY vmcnt traffic in the loop is the 4 stage loads:
//     keeps the counted wait exact.
// ---------------------------------------------------------------------------
__global__ __launch_bounds__(256) void main_kernel(
    const float* __restrict__ S_poly, const float* __restrict__ S_graph,
    const float* __restrict__ Wt, float* __restrict__ out)
{
    __shared__ float sbuf[2][KB][1024];   // 32 KB
    __shared__ float wlds[KTOT * TM];     // 3.75 KB

    const int t    = threadIdx.x;
    const int id   = blockIdx.x;      // 0..1023
    const int xcd  = id & 7;
    const int slot = id >> 3;         // 0..127
    const int xb   = xcd * 8 + (slot & 7);  // 0..63  (8 x-slices per XCD)
    const int yb   = slot >> 3;             // 0..15

    const int ij = xb * 1024 + t * 4;
    const int b0 = yb * TM;

    // W slice (60 k x 16 b) -> LDS once; single barrier, then barrier-free.
    for (int i = t; i < KTOT * TM; i += 256)
        wlds[i] = Wt[(i >> 4) * BATCH + b0 + (i & 15)];
    __syncthreads();

    f32x4 acc[TM];
    #pragma unroll
    for (int b = 0; b < TM; ++b) acc[b] = (f32x4)(0.f);

    // Per-wave LDS dest base: wave-uniform, lane l lands at +l*16 bytes.
    const int wbase = (t >> 6) << 8;  // wave * 256 floats

    auto stage = [&](int T, int d) {
        const int kb = T * KB;
        const float* base = (T < PF / KB)
            ? (S_poly  + (size_t)kb * OPD2)
            : (S_graph + (size_t)(kb - PF) * OPD2);
        const float* src = base + ij;   // per-lane 16B
        #pragma unroll
        for (int kk = 0; kk < KB; ++kk) {
            __builtin_amdgcn_global_load_lds(
                (const __attribute__((address_space(1))) uint32_t*)(src + (size_t)kk * OPD2),
                (__attribute__((address_space(3))) uint32_t*)&sbuf[d][kk][wbase],
                16, 0, 0);
        }
    };

    auto tile_fma = [&](int T, int buf) {
        // capture S tile into regs
        f32x4 sv[KB];
        #pragma unroll
        for (int kk = 0; kk < KB; ++kk)
            sv[kk] = *reinterpret_cast<const f32x4*>(&sbuf[buf][kk][t * 4]);
        // buffer free once the ds_reads completed -> safe to restage into it
        asm volatile("s_waitcnt lgkmcnt(0)" ::: "memory");
        __builtin_amdgcn_sched_barrier(0);
        if (T + 2 < NT) stage(T + 2, buf);
        // 256 FMAs, W broadcast from LDS (same-address = conflict-free)
        #pragma unroll
        for (int kk = 0; kk < KB; ++kk) {
            const float* wk = &wlds[(T * KB + kk) * TM];
            const f32x4 w0 = *reinterpret_cast<const f32x4*>(wk);
            const f32x4 w1 = *reinterpret_cast<const f32x4*>(wk + 4);
            const f32x4 w2 = *reinterpret_cast<const f32x4*>(wk + 8);
            const f32x4 w3 = *reinterpret_cast<const f32x4*>(wk + 12);
            const f32x4 s  = sv[kk];
            acc[0]  += w0.x * s;  acc[1]  += w0.y * s;
            acc[2]  += w0.z * s;  acc[3]  += w0.w * s;
            acc[4]  += w1.x * s;  acc[5]  += w1.y * s;
            acc[6]  += w1.z * s;  acc[7]  += w1.w * s;
            acc[8]  += w2.x * s;  acc[9]  += w2.y * s;
            acc[10] += w2.z * s;  acc[11] += w2.w * s;
            acc[12] += w3.x * s;  acc[13] += w3.y * s;
            acc[14] += w3.z * s;  acc[15] += w3.w * s;
        }
    };

    // prologue: depth-2 prefetch
    stage(0, 0);
    stage(1, 1);

    #pragma unroll 1
    for (int T = 0; T < NT - 1; ++T) {
        asm volatile("s_waitcnt vmcnt(4)" ::: "memory");  // tile T landed; T+1 in flight
        tile_fma(T, T & 1);
    }
    asm volatile("s_waitcnt vmcnt(0)" ::: "memory");      // last tile
    tile_fma(NT - 1, (NT - 1) & 1);

    #pragma unroll
    for (int b = 0; b < TM; ++b) {
        __builtin_nontemporal_store(
            acc[b],
            reinterpret_cast<f32x4*>(out + (size_t)(b0 + b) * OPD2 + ij));
    }
}

// ---------------------------------------------------------------------------
extern "C" void kernel_launch(void* const* d_in, const int* in_sizes, int n_in,
                              void* d_out, int out_size, void* d_ws, size_t ws_size,
                              hipStream_t stream) {
    const float* positions   = (const float*)d_in[0];  // (256, 2)
    const float* obs_pos     = (const float*)d_in[1];  // (2048, 2)
    const float* poly_dic    = (const float*)d_in[2];  // (2048, 28)
    const float* graph_dic   = (const float*)d_in[3];  // (2048, 512)
    const float* alpha_poly  = (const float*)d_in[4];  // (28, 28)
    const float* alpha_graph = (const float*)d_in[5];  // (512, 32)
    const float* S_poly      = (const float*)d_in[6];  // (28, 256, 256)
    const float* S_graph     = (const float*)d_in[7];  // (32, 256, 256)
    float* out = (float*)d_out;                        // (256, 256, 256)

    float* Wt = (float*)d_ws;  // KTOT * BATCH floats = 60 KB

    prep_kernel<<<BATCH, 256, 0, stream>>>(positions, obs_pos, poly_dic,
                                           graph_dic, alpha_poly, alpha_graph,
                                           Wt);

    main_kernel<<<1024, 256, 0, stream>>>(S_poly, S_graph, Wt, out);
}

// Round 5
// 127.680 us; speedup vs baseline: 1.0047x; 1.0047x over previous
//
#include <hip/hip_runtime.h>

// Problem constants (from reference)
#define NSTARS 2048
#define BATCH  256
#define PF     28
#define NGE    512
#define GF     32
#define OPD2   65536   // 256*256
#define KTOT   (PF + GF)  // 60
#define TM     16      // batches per block in main kernel
#define KB     4       // k-slices per LDS tile
#define NT     (KTOT / KB)  // 15 tiles: 0..6 = S_poly (28 k), 7..14 = S_graph (32 k)

typedef float f32x4 __attribute__((ext_vector_type(4)));

// ---------------------------------------------------------------------------
// Kernel 1: index search + W = [interm_poly | interm_graph] (k-major layout)
// Wt[k*BATCH + b], k in [0,60)
// ---------------------------------------------------------------------------
__global__ __launch_bounds__(256) void prep_kernel(
    const float* __restrict__ positions,  const float* __restrict__ obs_pos,
    const float* __restrict__ poly_dic,   const float* __restrict__ graph_dic,
    const float* __restrict__ alpha_poly, const float* __restrict__ alpha_graph,
    float* __restrict__ Wt)
{
    const int b = blockIdx.x;   // batch row
    const int t = threadIdx.x;  // 256 threads

    const float p0 = positions[2 * b];
    const float p1 = positions[2 * b + 1];

    // Faithful to argmax(eq.reshape(B,-1))//2 : first star n (row-major over
    // (n, coord)) where EITHER coordinate matches; all-false -> 0.
    int cand = 0x7fffffff;
    #pragma unroll
    for (int i = 0; i < NSTARS / 256; ++i) {
        const int n = t + i * 256;
        const float o0 = obs_pos[2 * n];
        const float o1 = obs_pos[2 * n + 1];
        if (o0 == p0 || o1 == p1) cand = min(cand, n);
    }
    __shared__ int smin[256];
    smin[t] = cand;
    __syncthreads();
    for (int s = 128; s > 0; s >>= 1) {
        if (t < s) smin[t] = min(smin[t], smin[t + s]);
        __syncthreads();
    }
    int idx = smin[0];
    if (idx == 0x7fffffff) idx = 0;  // argmax of all-False returns 0

    // interm_poly[j] = sum_p poly_dic[idx,p] * alpha_poly[p,j]
    if (t < PF) {
        float acc = 0.f;
        #pragma unroll
        for (int p = 0; p < PF; ++p)
            acc += poly_dic[idx * PF + p] * alpha_poly[p * PF + t];
        Wt[t * BATCH + b] = acc;
    }

    // interm_graph[g] = sum_e graph_dic[idx,e] * alpha_graph[e,g]
    // 8 partials of 64 elements each, reduced in LDS.
    __shared__ float psum[8][GF];
    {
        const int g = t & 31;
        const int r = t >> 5;
        float acc = 0.f;
        const int e0 = r * (NGE / 8);
        for (int e = e0; e < e0 + NGE / 8; ++e)
            acc += graph_dic[idx * NGE + e] * alpha_graph[e * GF + g];
        psum[r][g] = acc;
    }
    __syncthreads();
    if (t < GF) {
        float acc = 0.f;
        #pragma unroll
        for (int r = 0; r < 8; ++r) acc += psum[r][t];
        Wt[(PF + t) * BATCH + b] = acc;
    }
}

// ---------------------------------------------------------------------------
// Kernel 2: out[b, ij] = sum_k Wt[k, b] * S[k, ij]
// TM=16 batches x 1024 ij per block, 1024 blocks, XCD-swizzled.
//
// Barrier-free counted-vmcnt pipeline:
//   - each wave stages its OWN 64 lanes' float4s via global_load_lds and
//     reads back only that region -> no cross-wave sharing -> zero barriers.
//   - depth-2 prefetch: tiles T and T+1 in flight; per-tile wait
//     s_waitcnt vmcnt(4) -- never drained to 0 in the loop.
//   - W reads are block-uniform global loads with compile-time offsets ->
//     compiler emits s_load_dwordx16 into SGPRs (scalar cache, lgkmcnt
//     domain: does NOT pollute the counted vmcnt, costs zero VALU/LDS).
//     R4's LDS-broadcast W was ~16 us of LDS-pipe occupancy per CU --
//     above the 12.8 us VALU floor; this removes it.
// ---------------------------------------------------------------------------
__global__ __launch_bounds__(256) void main_kernel(
    const float* __restrict__ S_poly, const float* __restrict__ S_graph,
    const float* __restrict__ Wt, float* __restrict__ out)
{
    __shared__ float sbuf[2][KB][1024];   // 32 KB

    const int t    = threadIdx.x;
    const int id   = blockIdx.x;      // 0..1023
    const int xcd  = id & 7;
    const int slot = id >> 3;         // 0..127
    const int xb   = xcd * 8 + (slot & 7);  // 0..63  (8 x-slices per XCD)
    const int yb   = slot >> 3;             // 0..15

    const int ij = xb * 1024 + t * 4;
    const int b0 = yb * TM;

    const float* __restrict__ wp = Wt + b0;   // block-uniform -> s_load

    f32x4 acc[TM];
    #pragma unroll
    for (int b = 0; b < TM; ++b) acc[b] = (f32x4)(0.f);

    // Per-wave LDS dest base: wave-uniform, lane l lands at +l*16 bytes.
    const int wbase = (t >> 6) << 8;  // wave * 256 floats

    auto stage = [&](int T, int d) {
        const int kb = T * KB;
        const float* base = (T < PF / KB)
            ? (S_poly  + (size_t)kb * OPD2)
            : (S_graph + (size_t)(kb - PF) * OPD2);
        const float* src = base + ij;   // per-lane 16B
        #pragma unroll
        for (int kk = 0; kk < KB; ++kk) {
            __builtin_amdgcn_global_load_lds(
                (const __attribute__((address_space(1))) uint32_t*)(src + (size_t)kk * OPD2),
                (__attribute__((address_space(3))) uint32_t*)&sbuf[d][kk][wbase],
                16, 0, 0);
        }
    };

    auto tile_fma = [&](int T, int buf) {
        // capture S tile into regs (4x ds_read_b128, own lanes, conflict-free)
        f32x4 sv[KB];
        #pragma unroll
        for (int kk = 0; kk < KB; ++kk)
            sv[kk] = *reinterpret_cast<const f32x4*>(&sbuf[buf][kk][t * 4]);
        // ds_reads complete -> safe to DMA-restage into this buffer
        asm volatile("s_waitcnt lgkmcnt(0)" ::: "memory");
        __builtin_amdgcn_sched_barrier(0);
        if (T + 2 < NT) stage(T + 2, buf);
        // 256 FMAs; W from SGPRs (s_load_dwordx16 per kk, scalar cache)
        #pragma unroll
        for (int kk = 0; kk < KB; ++kk) {
            const float* wk = wp + (T * KB + kk) * BATCH;  // uniform address
            const f32x4 s = sv[kk];
            #pragma unroll
            for (int b = 0; b < TM; ++b)
                acc[b] += wk[b] * s;
        }
    };

    // prologue: depth-2 prefetch
    stage(0, 0);
    stage(1, 1);

    #pragma unroll 1
    for (int T = 0; T < NT - 1; ++T) {
        asm volatile("s_waitcnt vmcnt(4)" ::: "memory");  // tile T landed; T+1 flying
        tile_fma(T, T & 1);
    }
    asm volatile("s_waitcnt vmcnt(0)" ::: "memory");      // last tile
    tile_fma(NT - 1, (NT - 1) & 1);

    #pragma unroll
    for (int b = 0; b < TM; ++b) {
        __builtin_nontemporal_store(
            acc[b],
            reinterpret_cast<f32x4*>(out + (size_t)(b0 + b) * OPD2 + ij));
    }
}

// ---------------------------------------------------------------------------
extern "C" void kernel_launch(void* const* d_in, const int* in_sizes, int n_in,
                              void* d_out, int out_size, void* d_ws, size_t ws_size,
                              hipStream_t stream) {
    const float* positions   = (const float*)d_in[0];  // (256, 2)
    const float* obs_pos     = (const float*)d_in[1];  // (2048, 2)
    const float* poly_dic    = (const float*)d_in[2];  // (2048, 28)
    const float* graph_dic   = (const float*)d_in[3];  // (2048, 512)
    const float* alpha_poly  = (const float*)d_in[4];  // (28, 28)
    const float* alpha_graph = (const float*)d_in[5];  // (512, 32)
    const float* S_poly      = (const float*)d_in[6];  // (28, 256, 256)
    const float* S_graph     = (const float*)d_in[7];  // (32, 256, 256)
    float* out = (float*)d_out;                        // (256, 256, 256)

    float* Wt = (float*)d_ws;  // KTOT * BATCH floats = 60 KB

    prep_kernel<<<BATCH, 256, 0, stream>>>(positions, obs_pos, poly_dic,
                                           graph_dic, alpha_poly, alpha_graph,
                                           Wt);

    main_kernel<<<1024, 256, 0, stream>>>(S_poly, S_graph, Wt, out);
}

// Round 6
// 124.213 us; speedup vs baseline: 1.0327x; 1.0279x over previous
//
#include <hip/hip_runtime.h>

// Problem constants (from reference)
#define NSTARS 2048
#define BATCH  256
#define PF     28
#define NGE    512
#define GF     32
#define OPD2   65536   // 256*256
#define KTOT   (PF + GF)  // 60
#define TM     8       // batches per block (acc = 32 VGPR -> high occupancy)
#define DEPTH  6       // register pipeline depth (60 % 6 == 0)
#define NGRP   (KTOT / DEPTH)  // 10 groups of 6 k-slices

typedef float f32x4 __attribute__((ext_vector_type(4)));

// ---------------------------------------------------------------------------
// Kernel 1: index search + W = [interm_poly | interm_graph] (k-major layout)
// Wt[k*BATCH + b], k in [0,60)
// ---------------------------------------------------------------------------
__global__ __launch_bounds__(256) void prep_kernel(
    const float* __restrict__ positions,  const float* __restrict__ obs_pos,
    const float* __restrict__ poly_dic,   const float* __restrict__ graph_dic,
    const float* __restrict__ alpha_poly, const float* __restrict__ alpha_graph,
    float* __restrict__ Wt)
{
    const int b = blockIdx.x;   // batch row
    const int t = threadIdx.x;  // 256 threads

    const float p0 = positions[2 * b];
    const float p1 = positions[2 * b + 1];

    // Faithful to argmax(eq.reshape(B,-1))//2 : first star n (row-major over
    // (n, coord)) where EITHER coordinate matches; all-false -> 0.
    int cand = 0x7fffffff;
    #pragma unroll
    for (int i = 0; i < NSTARS / 256; ++i) {
        const int n = t + i * 256;
        const float o0 = obs_pos[2 * n];
        const float o1 = obs_pos[2 * n + 1];
        if (o0 == p0 || o1 == p1) cand = min(cand, n);
    }
    __shared__ int smin[256];
    smin[t] = cand;
    __syncthreads();
    for (int s = 128; s > 0; s >>= 1) {
        if (t < s) smin[t] = min(smin[t], smin[t + s]);
        __syncthreads();
    }
    int idx = smin[0];
    if (idx == 0x7fffffff) idx = 0;  // argmax of all-False returns 0

    // interm_poly[j] = sum_p poly_dic[idx,p] * alpha_poly[p,j]
    if (t < PF) {
        float acc = 0.f;
        #pragma unroll
        for (int p = 0; p < PF; ++p)
            acc += poly_dic[idx * PF + p] * alpha_poly[p * PF + t];
        Wt[t * BATCH + b] = acc;
    }

    // interm_graph[g] = sum_e graph_dic[idx,e] * alpha_graph[e,g]
    // 8 partials of 64 elements each, reduced in LDS.
    __shared__ float psum[8][GF];
    {
        const int g = t & 31;
        const int r = t >> 5;
        float acc = 0.f;
        const int e0 = r * (NGE / 8);
        for (int e = e0; e < e0 + NGE / 8; ++e)
            acc += graph_dic[idx * NGE + e] * alpha_graph[e * GF + g];
        psum[r][g] = acc;
    }
    __syncthreads();
    if (t < GF) {
        float acc = 0.f;
        #pragma unroll
        for (int r = 0; r < 8; ++r) acc += psum[r][t];
        Wt[(PF + t) * BATCH + b] = acc;
    }
}

// ---------------------------------------------------------------------------
// Kernel 2: out[b, ij] = sum_k Wt[k, b] * S[k, ij]
// TM=8 batches x 1024 ij per block, 2048 blocks, bijective XCD swizzle
// (per-XCD S footprint = 8 slices x 240 KB = 1.92 MB, L2-resident, 32x reuse).
//
// Design rationale (R0-R5 ledger: six schedules, all ~37-45 us):
//  - TLP over ILP: no LDS data path, no hand waitcnts. S goes global->reg
//    through an explicit 6-deep rotating pipeline (named regs, compile-time
//    indices); 20 waves/CU hide the residual latency in hardware.
//  - Store-burst fix: all previous variants were a SINGLE co-resident
//    generation -> 67 MB drained serially at kernel end (~11 us). The dead
//    32 KB LDS array caps residency at 5 blocks/CU, so the 8 blocks/CU of
//    work run as ragged generations (5+3): gen-1 stores overlap gen-2
//    compute.
//  - W stays on the scalar path (block-uniform -> s_load, lgkm domain).
// ---------------------------------------------------------------------------
__global__ __launch_bounds__(256) void main_kernel(
    const float* __restrict__ S_poly, const float* __restrict__ S_graph,
    const float* __restrict__ Wt, float* __restrict__ out)
{
    __shared__ float lds_throttle[8192];  // 32 KB: residency cap = 5 blocks/CU

    const int t    = threadIdx.x;
    const int id   = blockIdx.x;            // 0..2047
    const int xcd  = id & 7;
    const int slot = id >> 3;               // 0..255
    const int xb   = xcd * 8 + (slot & 7);  // 0..63  (8 x-slices per XCD)
    const int yb   = slot >> 3;             // 0..31
    const int ij   = xb * 1024 + t * 4;
    const int b0   = yb * TM;

    // Opaque never-true guard keeps the LDS allocation live without traffic.
    if (id == -1) lds_throttle[t] = Wt[t];

    const float* __restrict__ wp = Wt + b0;  // block-uniform -> s_load

    f32x4 acc[TM];
    #pragma unroll
    for (int b = 0; b < TM; ++b) acc[b] = (f32x4)(0.f);

    // Address of this thread's float4 in S slice k (scalar poly/graph select).
    auto srow = [&](int k) -> const f32x4* {
        const float* base = (k < PF) ? (S_poly  + (size_t)k * OPD2)
                                     : (S_graph + (size_t)(k - PF) * OPD2);
        return reinterpret_cast<const f32x4*>(base + ij);
    };

    // one k-step: FMA with sv, then (optionally) reload sv with slice k+DEPTH
    auto kstep = [&](int k, f32x4& sv, bool reload) {
        const float* wk = wp + k * BATCH;   // uniform -> s_load_dwordx8
        const f32x4 s = sv;
        #pragma unroll
        for (int b = 0; b < TM; ++b)
            acc[b] += wk[b] * s;
        if (reload) sv = *srow(k + DEPTH);
    };

    // prologue: fill the 6-deep pipeline
    f32x4 sv0 = *srow(0), sv1 = *srow(1), sv2 = *srow(2),
          sv3 = *srow(3), sv4 = *srow(4), sv5 = *srow(5);

    #pragma unroll 1
    for (int T = 0; T < NGRP - 1; ++T) {
        const int kg = T * DEPTH;
        kstep(kg + 0, sv0, true);
        kstep(kg + 1, sv1, true);
        kstep(kg + 2, sv2, true);
        kstep(kg + 3, sv3, true);
        kstep(kg + 4, sv4, true);
        kstep(kg + 5, sv5, true);
    }
    {   // last group: drain, no reload
        const int kg = (NGRP - 1) * DEPTH;
        kstep(kg + 0, sv0, false);
        kstep(kg + 1, sv1, false);
        kstep(kg + 2, sv2, false);
        kstep(kg + 3, sv3, false);
        kstep(kg + 4, sv4, false);
        kstep(kg + 5, sv5, false);
    }

    #pragma unroll
    for (int b = 0; b < TM; ++b) {
        __builtin_nontemporal_store(
            acc[b],
            reinterpret_cast<f32x4*>(out + (size_t)(b0 + b) * OPD2 + ij));
    }
}

// ---------------------------------------------------------------------------
extern "C" void kernel_launch(void* const* d_in, const int* in_sizes, int n_in,
                              void* d_out, int out_size, void* d_ws, size_t ws_size,
                              hipStream_t stream) {
    const float* positions   = (const float*)d_in[0];  // (256, 2)
    const float* obs_pos     = (const float*)d_in[1];  // (2048, 2)
    const float* poly_dic    = (const float*)d_in[2];  // (2048, 28)
    const float* graph_dic   = (const float*)d_in[3];  // (2048, 512)
    const float* alpha_poly  = (const float*)d_in[4];  // (28, 28)
    const float* alpha_graph = (const float*)d_in[5];  // (512, 32)
    const float* S_poly      = (const float*)d_in[6];  // (28, 256, 256)
    const float* S_graph     = (const float*)d_in[7];  // (32, 256, 256)
    float* out = (float*)d_out;                        // (256, 256, 256)

    float* Wt = (float*)d_ws;  // KTOT * BATCH floats = 60 KB

    prep_kernel<<<BATCH, 256, 0, stream>>>(positions, obs_pos, poly_dic,
                                           graph_dic, alpha_poly, alpha_graph,
                                           Wt);

    main_kernel<<<2048, 256, 0, stream>>>(S_poly, S_graph, Wt, out);
}